// Round 1
// baseline (218.903 us; speedup 1.0000x reference)
//
#include <hip/hip_runtime.h>

// Shapes (fixed by setup_inputs): x [T=4, B=16, C=512, N=1024] fp32
// out [T,B,C,1] = [64, 512] fp32
#define T_  4
#define B_  16
#define C_  512
#define N_  1024
#define CR_ 64

static constexpr float BN_EPS = 1e-5f;

typedef float f4_t __attribute__((ext_vector_type(4)));  // native vec for nontemporal builtin

// ---------------------------------------------------------------------------
// K1: LIF 4-step recurrence + global-average-pool over N.
// One block per (b, c): 256 threads x float4 = 1024 = N elements.
// v <- (v + x_t) * 0.5 ; s = (v >= 1) ; v = s ? 0 : v   [hard reset]
// All 4 plane loads are issued before the recurrence so 4 NT loads are in
// flight per thread (64 B/thread, pure streaming).
// Spike counting via ballot+popcount: spikes are {0,1}, so popcount over the
// 64-bit ballot mask is the exact lane-sum (scalar pipe, no LDS butterfly).
// Also zeroes K2's spin flag (stream-ordered before K2 launches).
// ---------------------------------------------------------------------------
__global__ __launch_bounds__(256) void lif_gap_kernel(
    const float* __restrict__ x, float* __restrict__ g, int* __restrict__ flag) {
    const int blk = blockIdx.x;          // b*C + c ; consecutive blocks read consecutive 4KB chunks
    const int tid = threadIdx.x;
    if (blk == 0 && tid == 0) *flag = 0; // reset K2 producer/consumer flag each iteration
    const int b   = blk >> 9;            // / 512
    const int c   = blk & (C_ - 1);
    const size_t plane = (size_t)B_ * C_ * N_;
    const float* __restrict__ xp = x + ((size_t)(b * C_ + c)) * N_ + (size_t)tid * 4;

    f4_t xv[T_];
#pragma unroll
    for (int t = 0; t < T_; ++t)
        xv[t] = __builtin_nontemporal_load((const f4_t*)(xp + (size_t)t * plane));

    f4_t v = (f4_t)(0.f);
    int cnt[T_];
#pragma unroll
    for (int t = 0; t < T_; ++t) {
        v.x = 0.5f * (v.x + xv[t].x);
        v.y = 0.5f * (v.y + xv[t].y);
        v.z = 0.5f * (v.z + xv[t].z);
        v.w = 0.5f * (v.w + xv[t].w);
        const unsigned long long m0 = __ballot(v.x >= 1.0f);
        const unsigned long long m1 = __ballot(v.y >= 1.0f);
        const unsigned long long m2 = __ballot(v.z >= 1.0f);
        const unsigned long long m3 = __ballot(v.w >= 1.0f);
        cnt[t] = (int)(__popcll(m0) + __popcll(m1) + __popcll(m2) + __popcll(m3));
        v.x = (v.x >= 1.0f) ? 0.f : v.x;
        v.y = (v.y >= 1.0f) ? 0.f : v.y;
        v.z = (v.z >= 1.0f) ? 0.f : v.z;
        v.w = (v.w >= 1.0f) ? 0.f : v.w;
    }

    __shared__ int lds[4 * T_];          // 4 waves x 4 t-counts
    const int wave = tid >> 6;
    const int lane = tid & 63;
    if (lane == 0) {
#pragma unroll
        for (int t = 0; t < T_; ++t) lds[wave * T_ + t] = cnt[t];
    }
    __syncthreads();
    if (tid < T_) {                      // thread tid finalizes timestep t = tid
        const int tot = lds[0 * T_ + tid] + lds[1 * T_ + tid] +
                        lds[2 * T_ + tid] + lds[3 * T_ + tid];
        g[((size_t)(tid * B_ + b)) * C_ + c] = (float)tot * (1.0f / N_);
    }
}

// ---------------------------------------------------------------------------
// K2 (fused fc1+BN1+fc2+BN2): 128 blocks x 256 threads.
// Phase A (blocks 0..63): h1[:,j] = BN1(g @ w1^T + b1)[:,j], column j = blockIdx.
//   Each wave covers 16 rows; 4 rows concurrently via 16-lane sub-groups
//   (dual accumulators shorten the FMA chain), then a 4-step shfl reduce.
//   After the column is in global h1: __threadfence() (agent fence = L2
//   writeback, required for cross-XCD visibility) + atomicAdd(flag).
// All blocks: tid 0 spins on flag==64 (s_sleep), then __threadfence()
//   (L2 invalidate) so plain h1 loads are fresh.
// Phase B (all 128 blocks): stage h1 into LDS [64][65] (pad -> worst 2-way
//   bank alias, which is free), wave w computes out column j2 = blk*4+w:
//   lane = row, 64-FMA dot against broadcast (scalar) w2 row, then butterfly
//   mean/var over the 64 rows held one-per-lane.
// 128 blocks < 256 CUs => all blocks resident => spin cannot deadlock.
// ---------------------------------------------------------------------------
__global__ __launch_bounds__(256) void fc_fused_kernel(
    const float* __restrict__ g,  const float* __restrict__ w1,
    const float* __restrict__ b1, const float* __restrict__ gamma1,
    const float* __restrict__ beta1,
    const float* __restrict__ w2, const float* __restrict__ b2,
    const float* __restrict__ gamma2, const float* __restrict__ beta2,
    float* __restrict__ h1, int* __restrict__ flag,
    float* __restrict__ out) {
    const int tid  = threadIdx.x;
    const int lane = tid & 63;
    const int wave = tid >> 6;
    __shared__ float rowval[64];
    __shared__ float h1s[64][65];        // +1 pad: bank = (65*row + k) % 32 varies with row

    if (blockIdx.x < CR_) {              // ---- Phase A: one h1 column per block
        const int j = blockIdx.x;
        const float* __restrict__ w1r = w1 + (size_t)j * C_;
        const int sub = lane >> 4;       // 16-lane sub-group -> row within quad
        const int kl  = lane & 15;
#pragma unroll
        for (int it = 0; it < 4; ++it) {
            const int r = wave * 16 + it * 4 + sub;      // rows 0..63 over 4 waves
            const float* __restrict__ gr = g + (size_t)r * C_;
            float p0 = 0.f, p1 = 0.f;
#pragma unroll
            for (int m = 0; m < 16; ++m) {
                const int k = kl + 32 * m;
                p0 += gr[k]      * w1r[k];
                p1 += gr[k + 16] * w1r[k + 16];
            }
            float p = p0 + p1;
            p += __shfl_xor(p, 1, 64);
            p += __shfl_xor(p, 2, 64);
            p += __shfl_xor(p, 4, 64);
            p += __shfl_xor(p, 8, 64);
            if (kl == 0) rowval[r] = p + b1[j];
        }
        __syncthreads();
        if (tid < 64) {                  // wave 0: BN1 over the 64 rows
            const float vv = rowval[tid];
            float s = vv, s2 = vv * vv;
#pragma unroll
            for (int off = 32; off >= 1; off >>= 1) {
                s  += __shfl_xor(s,  off, 64);
                s2 += __shfl_xor(s2, off, 64);
            }
            const float mu  = s * (1.f / 64.f);
            const float var = s2 * (1.f / 64.f) - mu * mu;
            h1[(size_t)tid * CR_ + j] =
                (vv - mu) * rsqrtf(var + BN_EPS) * gamma1[j] + beta1[j];
        }
        __syncthreads();                 // all h1 stores of this block done
        if (tid == 0) {
            __threadfence();             // agent acq_rel: L2 writeback before release
            atomicAdd(flag, 1);          // device-scope
        }
    }

    // ---- wait for all 64 producer columns
    if (tid == 0) {
        while (__hip_atomic_load(flag, __ATOMIC_RELAXED, __HIP_MEMORY_SCOPE_AGENT) < CR_)
            __builtin_amdgcn_s_sleep(8);
        __threadfence();                 // invalidate L2 -> fresh h1 on this XCD
    }
    __syncthreads();

    // ---- Phase B: stage h1 (16 KiB) into LDS, coalesced
    for (int e = tid; e < 64 * 64; e += 256)
        h1s[e >> 6][e & 63] = h1[e];
    __syncthreads();

    const int j2 = blockIdx.x * 4 + wave;            // 0..511
    const float* __restrict__ w2r = w2 + (size_t)j2 * CR_;
    float v = b2[j2];
#pragma unroll
    for (int k = 0; k < CR_; ++k)
        v += h1s[lane][k] * w2r[k];                  // w2r[k] uniform -> scalar load

    float s = v, s2 = v * v;
#pragma unroll
    for (int off = 32; off >= 1; off >>= 1) {
        s  += __shfl_xor(s,  off, 64);
        s2 += __shfl_xor(s2, off, 64);
    }
    const float mu  = s * (1.f / 64.f);
    const float var = s2 * (1.f / 64.f) - mu * mu;
    out[(size_t)lane * C_ + j2] =
        (v - mu) * rsqrtf(var + BN_EPS) * gamma2[j2] + beta2[j2];
}

extern "C" void kernel_launch(void* const* d_in, const int* in_sizes, int n_in,
                              void* d_out, int out_size, void* d_ws, size_t ws_size,
                              hipStream_t stream) {
    const float* x      = (const float*)d_in[0];
    const float* w1     = (const float*)d_in[1];
    const float* b1     = (const float*)d_in[2];
    const float* gamma1 = (const float*)d_in[3];
    const float* beta1  = (const float*)d_in[4];
    const float* w2     = (const float*)d_in[5];
    const float* b2     = (const float*)d_in[6];
    const float* gamma2 = (const float*)d_in[7];
    const float* beta2  = (const float*)d_in[8];
    float* out = (float*)d_out;

    float* g    = (float*)d_ws;          // [64, 512] = 128 KiB
    float* h1   = g + 64 * C_;           // [64, 64]  =  16 KiB
    int*   flag = (int*)(h1 + 64 * CR_); // 4 B producer/consumer counter

    lif_gap_kernel<<<B_ * C_, 256, 0, stream>>>(x, g, flag);
    fc_fused_kernel<<<128, 256, 0, stream>>>(g, w1, b1, gamma1, beta1,
                                             w2, b2, gamma2, beta2,
                                             h1, flag, out);
}

// Round 2
// 216.844 us; speedup vs baseline: 1.0095x; 1.0095x over previous
//
#include <hip/hip_runtime.h>

// Shapes (fixed by setup_inputs): x [T=4, B=16, C=512, N=1024] fp32
// out [T,B,C,1] = [64, 512] fp32
#define T_  4
#define B_  16
#define C_  512
#define N_  1024
#define CR_ 64
#define SW_ 4    // channels (b,c) per lif block

static constexpr float BN_EPS = 1e-5f;

typedef float f4_t __attribute__((ext_vector_type(4)));

// ---------------------------------------------------------------------------
// K1: LIF 4-step recurrence + global-average-pool over N.
// 2048 blocks x 256 threads; each block owns 4 CONSECUTIVE channels (b,c)
// (16 KiB contiguous per t-plane per block). All 16 float4 loads are issued
// up-front: 256 B/thread in flight, mirroring the grid-stride copy pattern
// that reaches 6.3 TB/s. Plain (cached) loads — x was evicted by the 512 MiB
// ws poison anyway, and the 6.3 TB/s ubench uses plain loads.
// v <- (v + x_t) * 0.5 ; s = (v >= 1) ; v = s ? 0 : v   [hard reset]
// Spike counting via ballot+popcount (exact lane-sum of {0,1} spikes,
// scalar pipe, wave-uniform result). One LDS tail for all 4 channels.
// ---------------------------------------------------------------------------
__global__ __launch_bounds__(256) void lif_gap_kernel(
    const float* __restrict__ x, float* __restrict__ g) {
    const int blk = blockIdx.x;          // 0..2047
    const int tid = threadIdx.x;
    const size_t plane = (size_t)B_ * C_ * N_;
    const int chan0 = blk * SW_;         // 4 consecutive (b*C+c) channels
    const float* __restrict__ xp = x + (size_t)chan0 * N_ + (size_t)tid * 4;

    // issue all 16 loads back-to-back (independent streams, max vmcnt depth)
    f4_t xv[SW_][T_];
#pragma unroll
    for (int s = 0; s < SW_; ++s)
#pragma unroll
        for (int t = 0; t < T_; ++t)
            xv[s][t] = *(const f4_t*)(xp + (size_t)s * N_ + (size_t)t * plane);

    int cnt[SW_][T_];
#pragma unroll
    for (int s = 0; s < SW_; ++s) {
        f4_t v = (f4_t)(0.f);
#pragma unroll
        for (int t = 0; t < T_; ++t) {
            v.x = 0.5f * (v.x + xv[s][t].x);
            v.y = 0.5f * (v.y + xv[s][t].y);
            v.z = 0.5f * (v.z + xv[s][t].z);
            v.w = 0.5f * (v.w + xv[s][t].w);
            const unsigned long long m0 = __ballot(v.x >= 1.0f);
            const unsigned long long m1 = __ballot(v.y >= 1.0f);
            const unsigned long long m2 = __ballot(v.z >= 1.0f);
            const unsigned long long m3 = __ballot(v.w >= 1.0f);
            cnt[s][t] = (int)(__popcll(m0) + __popcll(m1) + __popcll(m2) + __popcll(m3));
            v.x = (v.x >= 1.0f) ? 0.f : v.x;
            v.y = (v.y >= 1.0f) ? 0.f : v.y;
            v.z = (v.z >= 1.0f) ? 0.f : v.z;
            v.w = (v.w >= 1.0f) ? 0.f : v.w;
        }
    }

    __shared__ int lds[4][SW_][T_];      // [wave][chan][t]
    const int wave = tid >> 6;
    const int lane = tid & 63;
    if (lane == 0) {                     // cnt is wave-uniform; static indices only
#pragma unroll
        for (int s = 0; s < SW_; ++s)
#pragma unroll
            for (int t = 0; t < T_; ++t) lds[wave][s][t] = cnt[s][t];
    }
    __syncthreads();
    if (tid < SW_ * T_) {                // 16 finalizer threads: (s,t) pair each
        const int s = tid >> 2;
        const int t = tid & 3;
        const int tot = lds[0][s][t] + lds[1][s][t] + lds[2][s][t] + lds[3][s][t];
        const int chan = chan0 + s;
        const int b = chan >> 9;         // / C_
        const int c = chan & (C_ - 1);
        g[((size_t)(t * B_ + b)) * C_ + c] = (float)tot * (1.0f / N_);
    }
}

// ---------------------------------------------------------------------------
// K2: h1 = BN1(g @ w1^T + b1), h1 is [64 rows (TB), 64 cols (Cr)].
// One block per output column j (Cr). 4 waves; wave w computes rows w,w+4,...
// via length-512 dot with wave butterfly reduce. Then wave 0 does the
// batch-dim (64-row) mean/var and writes BN'd column.
// ---------------------------------------------------------------------------
__global__ __launch_bounds__(256) void fc1_bn_kernel(
    const float* __restrict__ g,  const float* __restrict__ w1,
    const float* __restrict__ b1, const float* __restrict__ gamma1,
    const float* __restrict__ beta1, float* __restrict__ h1) {
    const int j    = blockIdx.x;         // 0..63
    const int tid  = threadIdx.x;
    const int lane = tid & 63;
    const int wave = tid >> 6;
    __shared__ float rowval[64];

    const float* __restrict__ w1r = w1 + (size_t)j * C_;
    for (int i = wave; i < 64; i += 4) {
        float p = 0.f;
        const float* __restrict__ gr = g + (size_t)i * C_;
#pragma unroll
        for (int m = 0; m < C_ / 64; ++m) {
            const int k = lane + 64 * m;
            p += gr[k] * w1r[k];
        }
#pragma unroll
        for (int off = 32; off >= 1; off >>= 1) p += __shfl_xor(p, off, 64);
        if (lane == 0) rowval[i] = p + b1[j];
    }
    __syncthreads();
    if (tid < 64) {                      // exactly wave 0 (wavefront = 64)
        const float v = rowval[tid];
        float s  = v;
        float s2 = v * v;
#pragma unroll
        for (int off = 32; off >= 1; off >>= 1) {
            s  += __shfl_xor(s,  off, 64);
            s2 += __shfl_xor(s2, off, 64);
        }
        const float mu  = s * (1.f / 64.f);
        const float var = s2 * (1.f / 64.f) - mu * mu;
        h1[(size_t)tid * CR_ + j] =
            (v - mu) * rsqrtf(var + BN_EPS) * gamma1[j] + beta1[j];
    }
}

// ---------------------------------------------------------------------------
// K3: out = BN2(h1 @ w2^T + b2), out is [64 rows (TB), 512 cols (C)].
// One block (= one wave) per output column j; lane = row. Dot of length 64,
// then butterfly mean/var across the 64 rows held one-per-lane.
// ---------------------------------------------------------------------------
__global__ __launch_bounds__(64) void fc2_bn_kernel(
    const float* __restrict__ h1, const float* __restrict__ w2,
    const float* __restrict__ b2, const float* __restrict__ gamma2,
    const float* __restrict__ beta2, float* __restrict__ out) {
    const int j = blockIdx.x;            // 0..511
    const int i = threadIdx.x;           // row 0..63
    const float* __restrict__ w2r = w2 + (size_t)j * CR_;
    const float* __restrict__ hr  = h1 + (size_t)i * CR_;
    float v = b2[j];
#pragma unroll
    for (int k = 0; k < CR_; ++k) v += hr[k] * w2r[k];

    float s  = v;
    float s2 = v * v;
#pragma unroll
    for (int off = 32; off >= 1; off >>= 1) {
        s  += __shfl_xor(s,  off, 64);
        s2 += __shfl_xor(s2, off, 64);
    }
    const float mu  = s * (1.f / 64.f);
    const float var = s2 * (1.f / 64.f) - mu * mu;
    out[(size_t)i * C_ + j] =
        (v - mu) * rsqrtf(var + BN_EPS) * gamma2[j] + beta2[j];
}

extern "C" void kernel_launch(void* const* d_in, const int* in_sizes, int n_in,
                              void* d_out, int out_size, void* d_ws, size_t ws_size,
                              hipStream_t stream) {
    const float* x      = (const float*)d_in[0];
    const float* w1     = (const float*)d_in[1];
    const float* b1     = (const float*)d_in[2];
    const float* gamma1 = (const float*)d_in[3];
    const float* beta1  = (const float*)d_in[4];
    const float* w2     = (const float*)d_in[5];
    const float* b2     = (const float*)d_in[6];
    const float* gamma2 = (const float*)d_in[7];
    const float* beta2  = (const float*)d_in[8];
    float* out = (float*)d_out;

    float* g  = (float*)d_ws;            // [64, 512]  = 128 KiB
    float* h1 = g + 64 * C_;             // [64, 64]   =  16 KiB

    lif_gap_kernel<<<(B_ * C_) / SW_, 256, 0, stream>>>(x, g);
    fc1_bn_kernel<<<CR_, 256, 0, stream>>>(g, w1, b1, gamma1, beta1, h1);
    fc2_bn_kernel<<<C_, 64, 0, stream>>>(h1, w2, b2, gamma2, beta2, out);
}

// Round 3
// 211.752 us; speedup vs baseline: 1.0338x; 1.0240x over previous
//
#include <hip/hip_runtime.h>

// Shapes (fixed by setup_inputs): x [T=4, B=16, C=512, N=1024] fp32
// out [T,B,C,1] = [64, 512] fp32
#define T_  4
#define B_  16
#define C_  512
#define N_  1024
#define CR_ 64

static constexpr float BN_EPS = 1e-5f;

typedef float f4_t __attribute__((ext_vector_type(4)));  // native vec for nontemporal builtin

// ---------------------------------------------------------------------------
// K1: LIF 4-step recurrence + global-average-pool over N.  (exact R0 form —
// best measured; R2's 4-chan/block variant regressed, likely VGPR/occupancy.)
// One block per (b, c): 256 threads x float4 = 1024 = N elements.
// v <- (v + x_t) * 0.5 ; s = (v >= 1) ; v = s ? 0 : v   [hard reset]
// Spike counting via ballot+popcount (scalar pipe) — spikes are {0,1} so
// popcount over the 64-bit ballot mask is the exact lane-sum.
// g[(t*B + b)*C + c] = count / N
// ---------------------------------------------------------------------------
__global__ __launch_bounds__(256) void lif_gap_kernel(
    const float* __restrict__ x, float* __restrict__ g) {
    const int blk = blockIdx.x;          // b*C + c ; consecutive blocks read consecutive 4KB chunks
    const int b   = blk >> 9;            // / 512
    const int c   = blk & (C_ - 1);
    const int tid = threadIdx.x;
    const size_t plane = (size_t)B_ * C_ * N_;
    const float* __restrict__ xp = x + ((size_t)(b * C_ + c)) * N_ + (size_t)tid * 4;

    f4_t v = (f4_t)(0.f);
    int cnt[T_];
#pragma unroll
    for (int t = 0; t < T_; ++t) {
        const f4_t* p = (const f4_t*)(xp + (size_t)t * plane);
        const f4_t xv = __builtin_nontemporal_load(p);
        v.x = 0.5f * (v.x + xv.x);
        v.y = 0.5f * (v.y + xv.y);
        v.z = 0.5f * (v.z + xv.z);
        v.w = 0.5f * (v.w + xv.w);
        const unsigned long long m0 = __ballot(v.x >= 1.0f);
        const unsigned long long m1 = __ballot(v.y >= 1.0f);
        const unsigned long long m2 = __ballot(v.z >= 1.0f);
        const unsigned long long m3 = __ballot(v.w >= 1.0f);
        cnt[t] = (int)(__popcll(m0) + __popcll(m1) + __popcll(m2) + __popcll(m3));
        v.x = (v.x >= 1.0f) ? 0.f : v.x;
        v.y = (v.y >= 1.0f) ? 0.f : v.y;
        v.z = (v.z >= 1.0f) ? 0.f : v.z;
        v.w = (v.w >= 1.0f) ? 0.f : v.w;
    }

    __shared__ int lds[4 * T_];          // 4 waves x 4 t-counts
    const int wave = tid >> 6;
    const int lane = tid & 63;
    if (lane == 0) {
#pragma unroll
        for (int t = 0; t < T_; ++t) lds[wave * T_ + t] = cnt[t];
    }
    __syncthreads();
    if (tid < T_) {                      // thread tid finalizes timestep t = tid
        const int tot = lds[0 * T_ + tid] + lds[1 * T_ + tid] +
                        lds[2 * T_ + tid] + lds[3 * T_ + tid];
        g[((size_t)(tid * B_ + b)) * C_ + c] = (float)tot * (1.0f / N_);
    }
}

// ---------------------------------------------------------------------------
// K2: h1 = BN1(g @ w1^T + b1), h1 is [64 rows (TB), 64 cols (Cr)].
// One block per output column j. 4 waves; each wave handles 16 rows with
// 4 rows IN FLIGHT via 16-lane sub-groups + dual accumulators (serial row
// loop 16 -> 4 iterations; fc1 is latency-bound at 64 blocks). Verified
// inside R1's fused kernel (absmax 0.0).
// ---------------------------------------------------------------------------
__global__ __launch_bounds__(256) void fc1_bn_kernel(
    const float* __restrict__ g,  const float* __restrict__ w1,
    const float* __restrict__ b1, const float* __restrict__ gamma1,
    const float* __restrict__ beta1, float* __restrict__ h1) {
    const int j    = blockIdx.x;         // 0..63
    const int tid  = threadIdx.x;
    const int lane = tid & 63;
    const int wave = tid >> 6;
    __shared__ float rowval[64];

    const float* __restrict__ w1r = w1 + (size_t)j * C_;
    const int sub = lane >> 4;           // 16-lane sub-group -> row within quad
    const int kl  = lane & 15;
#pragma unroll
    for (int it = 0; it < 4; ++it) {
        const int r = wave * 16 + it * 4 + sub;   // rows 0..63 over 4 waves
        const float* __restrict__ gr = g + (size_t)r * C_;
        float p0 = 0.f, p1 = 0.f;
#pragma unroll
        for (int m = 0; m < 16; ++m) {
            const int k = kl + 32 * m;
            p0 += gr[k]      * w1r[k];
            p1 += gr[k + 16] * w1r[k + 16];
        }
        float p = p0 + p1;
        p += __shfl_xor(p, 1, 64);
        p += __shfl_xor(p, 2, 64);
        p += __shfl_xor(p, 4, 64);
        p += __shfl_xor(p, 8, 64);
        if (kl == 0) rowval[r] = p + b1[j];
    }
    __syncthreads();
    if (tid < 64) {                      // wave 0: BN1 over the 64 rows
        const float v = rowval[tid];
        float s  = v;
        float s2 = v * v;
#pragma unroll
        for (int off = 32; off >= 1; off >>= 1) {
            s  += __shfl_xor(s,  off, 64);
            s2 += __shfl_xor(s2, off, 64);
        }
        const float mu  = s * (1.f / 64.f);
        const float var = s2 * (1.f / 64.f) - mu * mu;
        h1[(size_t)tid * CR_ + j] =
            (v - mu) * rsqrtf(var + BN_EPS) * gamma1[j] + beta1[j];
    }
}

// ---------------------------------------------------------------------------
// K3: out = BN2(h1 @ w2^T + b2), out is [64 rows (TB), 512 cols (C)].
// 128 blocks x 256 threads, 4 columns per block. h1 (16 KiB) is staged into
// LDS [64][65] with COALESCED global loads (the old per-lane row gather was
// 64 uncoalesced 256B-strided gathers per wave). Pad -> worst 2-way bank
// alias, which is free. Wave w computes column j2 = blk*4 + w: lane = row,
// 64-FMA dot against broadcast (scalar) w2 row, then butterfly mean/var
// across the 64 rows held one-per-lane. Verified inside R1's fused kernel.
// ---------------------------------------------------------------------------
__global__ __launch_bounds__(256) void fc2_bn_kernel(
    const float* __restrict__ h1, const float* __restrict__ w2,
    const float* __restrict__ b2, const float* __restrict__ gamma2,
    const float* __restrict__ beta2, float* __restrict__ out) {
    const int tid  = threadIdx.x;
    const int lane = tid & 63;
    const int wave = tid >> 6;
    __shared__ float h1s[64][65];

    for (int e = tid; e < 64 * 64; e += 256)
        h1s[e >> 6][e & 63] = h1[e];
    __syncthreads();

    const int j2 = blockIdx.x * 4 + wave;            // 0..511
    const float* __restrict__ w2r = w2 + (size_t)j2 * CR_;
    float v = b2[j2];
#pragma unroll
    for (int k = 0; k < CR_; ++k)
        v += h1s[lane][k] * w2r[k];                  // w2r[k] uniform -> scalar load

    float s  = v;
    float s2 = v * v;
#pragma unroll
    for (int off = 32; off >= 1; off >>= 1) {
        s  += __shfl_xor(s,  off, 64);
        s2 += __shfl_xor(s2, off, 64);
    }
    const float mu  = s * (1.f / 64.f);
    const float var = s2 * (1.f / 64.f) - mu * mu;
    out[(size_t)lane * C_ + j2] =
        (v - mu) * rsqrtf(var + BN_EPS) * gamma2[j2] + beta2[j2];
}

extern "C" void kernel_launch(void* const* d_in, const int* in_sizes, int n_in,
                              void* d_out, int out_size, void* d_ws, size_t ws_size,
                              hipStream_t stream) {
    const float* x      = (const float*)d_in[0];
    const float* w1     = (const float*)d_in[1];
    const float* b1     = (const float*)d_in[2];
    const float* gamma1 = (const float*)d_in[3];
    const float* beta1  = (const float*)d_in[4];
    const float* w2     = (const float*)d_in[5];
    const float* b2     = (const float*)d_in[6];
    const float* gamma2 = (const float*)d_in[7];
    const float* beta2  = (const float*)d_in[8];
    float* out = (float*)d_out;

    float* g  = (float*)d_ws;            // [64, 512]  = 128 KiB
    float* h1 = g + 64 * C_;             // [64, 64]   =  16 KiB

    lif_gap_kernel<<<B_ * C_, 256, 0, stream>>>(x, g);
    fc1_bn_kernel<<<CR_, 256, 0, stream>>>(g, w1, b1, gamma1, beta1, h1);
    fc2_bn_kernel<<<C_ / 4, 256, 0, stream>>>(h1, w2, b2, gamma2, beta2, out);
}

// Round 4
// 207.822 us; speedup vs baseline: 1.0533x; 1.0189x over previous
//
#include <hip/hip_runtime.h>

// Shapes (fixed by setup_inputs): x [T=4, B=16, C=512, N=1024] fp32
// out [T,B,C,1] = [64, 512] fp32
// EXACT R0 champion revert (best measured: 207.5 us). R1 (fused-spin),
// R2 (lif 4ch/block), R3 (fc restructure) all regressed vs this.
#define T_  4
#define B_  16
#define C_  512
#define N_  1024
#define CR_ 64

static constexpr float BN_EPS = 1e-5f;

typedef float f4_t __attribute__((ext_vector_type(4)));  // native vec for nontemporal builtin

// ---------------------------------------------------------------------------
// K1: LIF 4-step recurrence + global-average-pool over N.
// One block per (b, c): 256 threads x float4 = 1024 = N elements.
// v <- (v + x_t) * 0.5 ; s = (v >= 1) ; v = s ? 0 : v   [hard reset]
// Spike counting via ballot+popcount (scalar pipe) instead of shfl butterfly
// (LDS pipe) — spikes are {0,1} so popcount over the 64-bit ballot mask is
// the exact lane-sum.
// g[(t*B + b)*C + c] = count / N
// ---------------------------------------------------------------------------
__global__ __launch_bounds__(256) void lif_gap_kernel(
    const float* __restrict__ x, float* __restrict__ g) {
    const int blk = blockIdx.x;          // b*C + c ; consecutive blocks read consecutive 4KB chunks
    const int b   = blk >> 9;            // / 512
    const int c   = blk & (C_ - 1);
    const int tid = threadIdx.x;
    const size_t plane = (size_t)B_ * C_ * N_;
    const float* __restrict__ xp = x + ((size_t)(b * C_ + c)) * N_ + (size_t)tid * 4;

    f4_t v = (f4_t)(0.f);
    int cnt[T_];
#pragma unroll
    for (int t = 0; t < T_; ++t) {
        const f4_t* p = (const f4_t*)(xp + (size_t)t * plane);
        const f4_t xv = __builtin_nontemporal_load(p);
        v.x = 0.5f * (v.x + xv.x);
        v.y = 0.5f * (v.y + xv.y);
        v.z = 0.5f * (v.z + xv.z);
        v.w = 0.5f * (v.w + xv.w);
        // lane-sum of spikes across the wave via ballot+popcount (no LDS pipe)
        const unsigned long long m0 = __ballot(v.x >= 1.0f);
        const unsigned long long m1 = __ballot(v.y >= 1.0f);
        const unsigned long long m2 = __ballot(v.z >= 1.0f);
        const unsigned long long m3 = __ballot(v.w >= 1.0f);
        cnt[t] = (int)(__popcll(m0) + __popcll(m1) + __popcll(m2) + __popcll(m3));
        // hard reset
        v.x = (v.x >= 1.0f) ? 0.f : v.x;
        v.y = (v.y >= 1.0f) ? 0.f : v.y;
        v.z = (v.z >= 1.0f) ? 0.f : v.z;
        v.w = (v.w >= 1.0f) ? 0.f : v.w;
    }

    __shared__ int lds[4 * T_];          // 4 waves x 4 t-counts
    const int wave = tid >> 6;
    const int lane = tid & 63;
    if (lane == 0) {
#pragma unroll
        for (int t = 0; t < T_; ++t) lds[wave * T_ + t] = cnt[t];
    }
    __syncthreads();
    if (tid < T_) {                      // thread tid finalizes timestep t = tid
        const int tot = lds[0 * T_ + tid] + lds[1 * T_ + tid] +
                        lds[2 * T_ + tid] + lds[3 * T_ + tid];
        g[((size_t)(tid * B_ + b)) * C_ + c] = (float)tot * (1.0f / N_);
    }
}

// ---------------------------------------------------------------------------
// K2: h1 = BN1(g @ w1^T + b1), h1 is [64 rows (TB), 64 cols (Cr)].
// One block per output column j (Cr). 4 waves; wave w computes rows w,w+4,...
// via length-512 dot with wave butterfly reduce. Then wave 0 does the
// batch-dim (64-row) mean/var and writes BN'd column.
// ---------------------------------------------------------------------------
__global__ __launch_bounds__(256) void fc1_bn_kernel(
    const float* __restrict__ g,  const float* __restrict__ w1,
    const float* __restrict__ b1, const float* __restrict__ gamma1,
    const float* __restrict__ beta1, float* __restrict__ h1) {
    const int j    = blockIdx.x;         // 0..63
    const int tid  = threadIdx.x;
    const int lane = tid & 63;
    const int wave = tid >> 6;
    __shared__ float rowval[64];

    const float* __restrict__ w1r = w1 + (size_t)j * C_;
    for (int i = wave; i < 64; i += 4) {
        float p = 0.f;
        const float* __restrict__ gr = g + (size_t)i * C_;
#pragma unroll
        for (int m = 0; m < C_ / 64; ++m) {
            const int k = lane + 64 * m;
            p += gr[k] * w1r[k];
        }
#pragma unroll
        for (int off = 32; off >= 1; off >>= 1) p += __shfl_xor(p, off, 64);
        if (lane == 0) rowval[i] = p + b1[j];
    }
    __syncthreads();
    if (tid < 64) {                      // exactly wave 0 (wavefront = 64)
        const float v = rowval[tid];
        float s  = v;
        float s2 = v * v;
#pragma unroll
        for (int off = 32; off >= 1; off >>= 1) {
            s  += __shfl_xor(s,  off, 64);
            s2 += __shfl_xor(s2, off, 64);
        }
        const float mu  = s * (1.f / 64.f);
        const float var = s2 * (1.f / 64.f) - mu * mu;
        h1[(size_t)tid * CR_ + j] =
            (v - mu) * rsqrtf(var + BN_EPS) * gamma1[j] + beta1[j];
    }
}

// ---------------------------------------------------------------------------
// K3: out = BN2(h1 @ w2^T + b2), out is [64 rows (TB), 512 cols (C)].
// One block (= one wave) per output column j; lane = row. Dot of length 64,
// then butterfly mean/var across the 64 rows held one-per-lane.
// ---------------------------------------------------------------------------
__global__ __launch_bounds__(64) void fc2_bn_kernel(
    const float* __restrict__ h1, const float* __restrict__ w2,
    const float* __restrict__ b2, const float* __restrict__ gamma2,
    const float* __restrict__ beta2, float* __restrict__ out) {
    const int j = blockIdx.x;            // 0..511
    const int i = threadIdx.x;           // row 0..63
    const float* __restrict__ w2r = w2 + (size_t)j * CR_;
    const float* __restrict__ hr  = h1 + (size_t)i * CR_;
    float v = b2[j];
#pragma unroll
    for (int k = 0; k < CR_; ++k) v += hr[k] * w2r[k];

    float s  = v;
    float s2 = v * v;
#pragma unroll
    for (int off = 32; off >= 1; off >>= 1) {
        s  += __shfl_xor(s,  off, 64);
        s2 += __shfl_xor(s2, off, 64);
    }
    const float mu  = s * (1.f / 64.f);
    const float var = s2 * (1.f / 64.f) - mu * mu;
    out[(size_t)i * C_ + j] =
        (v - mu) * rsqrtf(var + BN_EPS) * gamma2[j] + beta2[j];
}

extern "C" void kernel_launch(void* const* d_in, const int* in_sizes, int n_in,
                              void* d_out, int out_size, void* d_ws, size_t ws_size,
                              hipStream_t stream) {
    const float* x      = (const float*)d_in[0];
    const float* w1     = (const float*)d_in[1];
    const float* b1     = (const float*)d_in[2];
    const float* gamma1 = (const float*)d_in[3];
    const float* beta1  = (const float*)d_in[4];
    const float* w2     = (const float*)d_in[5];
    const float* b2     = (const float*)d_in[6];
    const float* gamma2 = (const float*)d_in[7];
    const float* beta2  = (const float*)d_in[8];
    float* out = (float*)d_out;

    float* g  = (float*)d_ws;            // [64, 512]  = 128 KiB
    float* h1 = g + 64 * C_;             // [64, 64]   =  16 KiB

    lif_gap_kernel<<<B_ * C_, 256, 0, stream>>>(x, g);
    fc1_bn_kernel<<<CR_, 256, 0, stream>>>(g, w1, b1, gamma1, beta1, h1);
    fc2_bn_kernel<<<C_, 64, 0, stream>>>(h1, w2, b2, gamma2, beta2, out);
}